// Round 1
// baseline (957.680 us; speedup 1.0000x reference)
//
#include <hip/hip_runtime.h>
#include <cmath>

#define TPB 128

constexpr int KN   = 8;     // spline knots
constexpr int NPAR = 23;    // 3K-1
constexpr int DD   = 32;    // DIM
constexpr int LL   = 31;    // DIM-1 conditioner layers
constexpr int HH   = 32;    // HID
constexpr float BND   = 3.0f;
constexpr float MINBW = 1e-3f;
constexpr float MIND  = 1e-3f;

__device__ __forceinline__ float fast_tanh(float x) {
    float ax = fminf(fabsf(x), 15.0f);
    float e  = __expf(2.0f * ax);
    float t  = 1.0f - 2.0f / (e + 1.0f);
    return copysignf(t, x);
}

__device__ __forceinline__ float softplus_f(float v) {
    return fmaxf(v, 0.0f) + log1pf(__expf(-fabsf(v)));
}

// Rational-quadratic spline for one scalar. p[0:8]=W logits, p[8:16]=H logits,
// p[16:23]=D logits (pre double-softplus). Returns z, accumulates logdet.
__device__ __forceinline__ float rqs_apply(float xv, const float* p, float& ldsum) {
    float cw[KN + 1], ch[KN + 1], der[KN + 1];

    // ---- bin widths: Wu = 2B*softmax(p[0:8]); widths = softmax(Wu) pinned ----
    {
        float m = p[0];
#pragma unroll
        for (int k = 1; k < KN; ++k) m = fmaxf(m, p[k]);
        float t0[KN]; float s = 0.f;
#pragma unroll
        for (int k = 0; k < KN; ++k) { t0[k] = __expf(p[k] - m); s += t0[k]; }
        float inv = (2.0f * BND) / s;          // == max(Wu), since max(t0)==1
        float e2[KN]; float s2 = 0.f;
#pragma unroll
        for (int k = 0; k < KN; ++k) { e2[k] = __expf(inv * (t0[k] - 1.0f)); s2 += e2[k]; }
        float fac = (1.0f - MINBW * KN) / s2;
        float c = 0.f;
        cw[0] = -BND;
#pragma unroll
        for (int k = 0; k < KN; ++k) { c += MINBW + fac * e2[k]; cw[k + 1] = 2.0f * BND * c - BND; }
        cw[KN] = BND;
    }
    // ---- bin heights (same, logits p[8:16]) ----
    {
        float m = p[KN];
#pragma unroll
        for (int k = 1; k < KN; ++k) m = fmaxf(m, p[KN + k]);
        float t0[KN]; float s = 0.f;
#pragma unroll
        for (int k = 0; k < KN; ++k) { t0[k] = __expf(p[KN + k] - m); s += t0[k]; }
        float inv = (2.0f * BND) / s;
        float e2[KN]; float s2 = 0.f;
#pragma unroll
        for (int k = 0; k < KN; ++k) { e2[k] = __expf(inv * (t0[k] - 1.0f)); s2 += e2[k]; }
        float fac = (1.0f - MINBW * KN) / s2;
        float c = 0.f;
        ch[0] = -BND;
#pragma unroll
        for (int k = 0; k < KN; ++k) { c += MINBW + fac * e2[k]; ch[k + 1] = 2.0f * BND * c - BND; }
        ch[KN] = BND;
    }
    // ---- knot derivatives: edges pinned to exactly 1.0 by construction ----
    der[0] = 1.0f; der[KN] = 1.0f;
#pragma unroll
    for (int k = 1; k < KN; ++k)
        der[k] = MIND + softplus_f(softplus_f(p[2 * KN + k - 1]));

    // ---- bin search (scan) + gather via selects ----
    float xc = fminf(fmaxf(xv, -BND), BND);
    float in_cw = cw[0], in_w = cw[1] - cw[0];
    float in_ch = ch[0], in_h = ch[1] - ch[0];
    float d0 = der[0], d1 = der[1];
#pragma unroll
    for (int k = 1; k < KN; ++k) {
        bool c = (xc >= cw[k]);
        in_cw = c ? cw[k]            : in_cw;
        in_w  = c ? (cw[k+1]-cw[k])  : in_w;
        in_ch = c ? ch[k]            : in_ch;
        in_h  = c ? (ch[k+1]-ch[k])  : in_h;
        d0    = c ? der[k]           : d0;
        d1    = c ? der[k+1]         : d1;
    }

    float th    = (xc - in_cw) / in_w;
    float delta = in_h / in_w;
    float tt    = th * (1.0f - th);
    float th2   = th * th;
    float num   = in_h * (delta * th2 + d0 * tt);
    float den   = delta + (d0 + d1 - 2.0f * delta) * tt;
    float z     = in_ch + num / den;
    float omt   = 1.0f - th;
    float dnum  = delta * delta * (d1 * th2 + 2.0f * delta * tt + d0 * omt * omt);
    float ldv   = __logf(dnum) - 2.0f * __logf(den);

    bool inside = (xv >= -BND) && (xv <= BND);
    ldsum += inside ? ldv : 0.0f;
    return inside ? z : xv;
}

extern "C" __global__ void __launch_bounds__(TPB)
nsf_ar_kernel(const float* __restrict__ x,
              const float* __restrict__ p0,
              const float* __restrict__ w1, const float* __restrict__ b1,
              const float* __restrict__ w2, const float* __restrict__ b2,
              const float* __restrict__ w3, const float* __restrict__ b3,
              float* __restrict__ zo, float* __restrict__ ldo)
{
    __shared__ __align__(16) float sX[TPB * 33];   // x tile, row stride 33 (bank-pad)
    __shared__ __align__(16) float sW1[LL * HH];
    __shared__ __align__(16) float sW2[HH * HH];
    __shared__ __align__(16) float sW3[HH * 24];   // rows padded 23->24 for float4
    __shared__ __align__(16) float sB1[HH];
    __shared__ __align__(16) float sB2[HH];
    __shared__ __align__(16) float sB3[24];
    __shared__ __align__(16) float sP0[24];

    const int tid = threadIdx.x;
    const long long bbase = (long long)blockIdx.x * TPB;

    // stage x tile (coalesced global read -> padded LDS)
    for (int j = tid; j < TPB * DD; j += TPB)
        sX[(j >> 5) * 33 + (j & 31)] = x[bbase * DD + j];
    if (tid < NPAR) sP0[tid] = p0[tid];
    __syncthreads();

    const long long b = bbase + tid;
    float ldsum = 0.0f;

    // dim 0: init_param spline
    {
        float pr[NPAR];
#pragma unroll
        for (int k = 0; k < NPAR; ++k) pr[k] = sP0[k];
        zo[b * DD + 0] = rqs_apply(sX[tid * 33 + 0], pr, ldsum);
    }

    for (int l = 0; l < LL; ++l) {
        __syncthreads();
        // ---- stage layer-l weights into LDS (coalesced) ----
        {
            const float* g1 = w1 + (size_t)l * LL * HH;
            for (int i = tid; i < LL * HH; i += TPB) sW1[i] = g1[i];
            const float* g2 = w2 + (size_t)l * HH * HH;
            for (int i = tid; i < HH * HH; i += TPB) sW2[i] = g2[i];
            const float* g3 = w3 + (size_t)l * HH * NPAR;
            for (int i = tid; i < HH * 24; i += TPB) {
                int r = i / 24, c = i - r * 24;
                sW3[i] = (c < NPAR) ? g3[r * NPAR + c] : 0.0f;
            }
            if (tid < HH)                    sB1[tid]       = b1[(size_t)l * HH + tid];
            if (tid >= 32 && tid < 64)       sB2[tid - 32]  = b2[(size_t)l * HH + tid - 32];
            if (tid >= 64 && tid < 64+NPAR)  sB3[tid - 64]  = b3[(size_t)l * NPAR + tid - 64];
            if (tid == 96)                   sB3[23]        = 0.0f;
        }
        __syncthreads();

        // ---- h1 = tanh(x[0:l+1] @ W1 + b1) ----
        float h1[HH];
#pragma unroll
        for (int j = 0; j < HH; ++j) h1[j] = sB1[j];
        for (int i = 0; i <= l; ++i) {
            float xi = sX[tid * 33 + i];
            const float4* wr = (const float4*)(&sW1[i * HH]);
#pragma unroll
            for (int q = 0; q < HH / 4; ++q) {
                float4 w = wr[q];
                h1[4*q+0] = fmaf(xi, w.x, h1[4*q+0]);
                h1[4*q+1] = fmaf(xi, w.y, h1[4*q+1]);
                h1[4*q+2] = fmaf(xi, w.z, h1[4*q+2]);
                h1[4*q+3] = fmaf(xi, w.w, h1[4*q+3]);
            }
        }
#pragma unroll
        for (int j = 0; j < HH; ++j) h1[j] = fast_tanh(h1[j]);

        // ---- h2 = tanh(h1 @ W2 + b2) ----
        float h2[HH];
#pragma unroll
        for (int j = 0; j < HH; ++j) h2[j] = sB2[j];
#pragma unroll 4
        for (int i = 0; i < HH; ++i) {
            float hi = h1[i];
            const float4* wr = (const float4*)(&sW2[i * HH]);
#pragma unroll
            for (int q = 0; q < HH / 4; ++q) {
                float4 w = wr[q];
                h2[4*q+0] = fmaf(hi, w.x, h2[4*q+0]);
                h2[4*q+1] = fmaf(hi, w.y, h2[4*q+1]);
                h2[4*q+2] = fmaf(hi, w.z, h2[4*q+2]);
                h2[4*q+3] = fmaf(hi, w.w, h2[4*q+3]);
            }
        }
#pragma unroll
        for (int j = 0; j < HH; ++j) h2[j] = fast_tanh(h2[j]);

        // ---- params = h2 @ W3 + b3 (rows padded to 24) ----
        float pr[24];
#pragma unroll
        for (int k = 0; k < 24; ++k) pr[k] = sB3[k];
#pragma unroll 4
        for (int i = 0; i < HH; ++i) {
            float hi = h2[i];
            const float4* wr = (const float4*)(&sW3[i * 24]);
#pragma unroll
            for (int q = 0; q < 6; ++q) {
                float4 w = wr[q];
                pr[4*q+0] = fmaf(hi, w.x, pr[4*q+0]);
                pr[4*q+1] = fmaf(hi, w.y, pr[4*q+1]);
                pr[4*q+2] = fmaf(hi, w.z, pr[4*q+2]);
                pr[4*q+3] = fmaf(hi, w.w, pr[4*q+3]);
            }
        }

        // ---- spline for dim l+1 ----
        zo[b * DD + (l + 1)] = rqs_apply(sX[tid * 33 + (l + 1)], pr, ldsum);
    }

    ldo[b] = ldsum;
}

extern "C" void kernel_launch(void* const* d_in, const int* in_sizes, int n_in,
                              void* d_out, int out_size, void* d_ws, size_t ws_size,
                              hipStream_t stream) {
    const float* x  = (const float*)d_in[0];
    const float* p0 = (const float*)d_in[1];
    const float* w1 = (const float*)d_in[2];
    const float* b1 = (const float*)d_in[3];
    const float* w2 = (const float*)d_in[4];
    const float* b2 = (const float*)d_in[5];
    const float* w3 = (const float*)d_in[6];
    const float* b3 = (const float*)d_in[7];

    const int batch = in_sizes[0] / DD;        // 65536
    float* zo  = (float*)d_out;
    float* ldo = zo + (size_t)batch * DD;

    const int blocks = (batch + TPB - 1) / TPB;
    hipLaunchKernelGGL(nsf_ar_kernel, dim3(blocks), dim3(TPB), 0, stream,
                       x, p0, w1, b1, w2, b2, w3, b3, zo, ldo);
}

// Round 2
// 369.568 us; speedup vs baseline: 2.5914x; 2.5914x over previous
//
#include <hip/hip_runtime.h>
#include <cmath>

constexpr int KN   = 8;     // spline knots
constexpr int NPAR = 23;    // 3K-1
constexpr int DD   = 32;    // DIM
constexpr int LL   = 31;    // DIM-1 conditioner layers
constexpr int HH   = 32;    // HID
constexpr float BND   = 3.0f;
constexpr float MINBW = 1e-3f;
constexpr float MIND  = 1e-3f;

#define LTPB 256   // layer-kernel block size

__device__ __forceinline__ float fast_tanh(float x) {
    float ax = fminf(fabsf(x), 15.0f);
    float e  = __expf(2.0f * ax);
    float t  = 1.0f - 2.0f / (e + 1.0f);
    return copysignf(t, x);
}

__device__ __forceinline__ float softplus_f(float v) {
    return fmaxf(v, 0.0f) + log1pf(__expf(-fabsf(v)));
}

// Rational-quadratic spline for one scalar. p[0:8]=W logits, p[8:16]=H logits,
// p[16:23]=D logits (pre double-softplus). Returns z, writes logdet.
__device__ __forceinline__ float rqs_apply(float xv, const float* p, float& ldout) {
    float cw[KN + 1], ch[KN + 1], der[KN + 1];

    // ---- bin widths: Wu = 2B*softmax(p[0:8]); widths = softmax(Wu) pinned ----
    {
        float m = p[0];
#pragma unroll
        for (int k = 1; k < KN; ++k) m = fmaxf(m, p[k]);
        float t0[KN]; float s = 0.f;
#pragma unroll
        for (int k = 0; k < KN; ++k) { t0[k] = __expf(p[k] - m); s += t0[k]; }
        float inv = (2.0f * BND) / s;          // == max(Wu), since max(t0)==1
        float e2[KN]; float s2 = 0.f;
#pragma unroll
        for (int k = 0; k < KN; ++k) { e2[k] = __expf(inv * (t0[k] - 1.0f)); s2 += e2[k]; }
        float fac = (1.0f - MINBW * KN) / s2;
        float c = 0.f;
        cw[0] = -BND;
#pragma unroll
        for (int k = 0; k < KN; ++k) { c += MINBW + fac * e2[k]; cw[k + 1] = 2.0f * BND * c - BND; }
        cw[KN] = BND;
    }
    // ---- bin heights (same, logits p[8:16]) ----
    {
        float m = p[KN];
#pragma unroll
        for (int k = 1; k < KN; ++k) m = fmaxf(m, p[KN + k]);
        float t0[KN]; float s = 0.f;
#pragma unroll
        for (int k = 0; k < KN; ++k) { t0[k] = __expf(p[KN + k] - m); s += t0[k]; }
        float inv = (2.0f * BND) / s;
        float e2[KN]; float s2 = 0.f;
#pragma unroll
        for (int k = 0; k < KN; ++k) { e2[k] = __expf(inv * (t0[k] - 1.0f)); s2 += e2[k]; }
        float fac = (1.0f - MINBW * KN) / s2;
        float c = 0.f;
        ch[0] = -BND;
#pragma unroll
        for (int k = 0; k < KN; ++k) { c += MINBW + fac * e2[k]; ch[k + 1] = 2.0f * BND * c - BND; }
        ch[KN] = BND;
    }
    // ---- knot derivatives: edges pinned to exactly 1.0 by construction ----
    der[0] = 1.0f; der[KN] = 1.0f;
#pragma unroll
    for (int k = 1; k < KN; ++k)
        der[k] = MIND + softplus_f(softplus_f(p[2 * KN + k - 1]));

    // ---- bin search (scan) + gather via selects ----
    float xc = fminf(fmaxf(xv, -BND), BND);
    float in_cw = cw[0], in_w = cw[1] - cw[0];
    float in_ch = ch[0], in_h = ch[1] - ch[0];
    float d0 = der[0], d1 = der[1];
#pragma unroll
    for (int k = 1; k < KN; ++k) {
        bool c = (xc >= cw[k]);
        in_cw = c ? cw[k]            : in_cw;
        in_w  = c ? (cw[k+1]-cw[k])  : in_w;
        in_ch = c ? ch[k]            : in_ch;
        in_h  = c ? (ch[k+1]-ch[k])  : in_h;
        d0    = c ? der[k]           : d0;
        d1    = c ? der[k+1]         : d1;
    }

    float th    = (xc - in_cw) / in_w;
    float delta = in_h / in_w;
    float tt    = th * (1.0f - th);
    float th2   = th * th;
    float num   = in_h * (delta * th2 + d0 * tt);
    float den   = delta + (d0 + d1 - 2.0f * delta) * tt;
    float z     = in_ch + num / den;
    float omt   = 1.0f - th;
    float dnum  = delta * delta * (d1 * th2 + 2.0f * delta * tt + d0 * omt * omt);
    float ldv   = __logf(dnum) - 2.0f * __logf(den);

    bool inside = (xv >= -BND) && (xv <= BND);
    ldout = inside ? ldv : 0.0f;
    return inside ? z : xv;
}

// ---------------- variant A: transpose -> per-(layer,batch) -> finalize ----

extern "C" __global__ void __launch_bounds__(256)
k_transpose_x(const float* __restrict__ x, float* __restrict__ xT, int B)
{
    __shared__ float t[64][33];
    const int bbase = blockIdx.x * 64;
    for (int idx = threadIdx.x; idx < 64 * 32; idx += 256) {
        int r = idx >> 5, c = idx & 31;
        t[r][c] = x[(size_t)bbase * 32 + idx];
    }
    __syncthreads();
    for (int idx = threadIdx.x; idx < 64 * 32; idx += 256) {
        int d = idx >> 6, bb = idx & 63;
        xT[(size_t)d * B + bbase + bb] = t[bb][d];
    }
}

// grid.x = B/LTPB, grid.y = 32 (ly). ly==0: init_param spline on x[:,0].
// ly>=1: conditioner layer l=ly-1 on x[:,0:ly], spline on x[:,ly].
extern "C" __global__ void __launch_bounds__(LTPB)
k_layer(const float* __restrict__ xT,
        const float* __restrict__ p0,
        const float* __restrict__ w1, const float* __restrict__ b1,
        const float* __restrict__ w2, const float* __restrict__ b2,
        const float* __restrict__ w3, const float* __restrict__ b3,
        float* __restrict__ zT, float* __restrict__ ldp, int B)
{
    __shared__ __align__(16) float sW1[LL * HH];
    __shared__ __align__(16) float sW2[HH * HH];
    __shared__ __align__(16) float sW3[HH * 24];   // rows padded 23->24 for float4
    __shared__ __align__(16) float sB1[HH];
    __shared__ __align__(16) float sB2[HH];
    __shared__ __align__(16) float sB3[24];

    const int tid = threadIdx.x;
    const int ly  = blockIdx.y;                    // output dim index 0..31
    const size_t b = (size_t)blockIdx.x * LTPB + tid;

    float pr[24];

    if (ly == 0) {
        // wave-uniform broadcast read of init_param (L1/scalar)
#pragma unroll
        for (int k = 0; k < NPAR; ++k) pr[k] = p0[k];
    } else {
        const int l = ly - 1;
        // ---- stage layer-l weights into LDS (coalesced; only ly rows of W1) ----
        {
            const float* g1 = w1 + (size_t)l * LL * HH;
            for (int i = tid; i < ly * HH; i += LTPB) sW1[i] = g1[i];
            const float* g2 = w2 + (size_t)l * HH * HH;
            for (int i = tid; i < HH * HH; i += LTPB) sW2[i] = g2[i];
            const float* g3 = w3 + (size_t)l * HH * NPAR;
            for (int i = tid; i < HH * 24; i += LTPB) {
                int r = i / 24, c = i - r * 24;
                sW3[i] = (c < NPAR) ? g3[r * NPAR + c] : 0.0f;
            }
            if (tid < HH)                         sB1[tid]      = b1[(size_t)l * HH + tid];
            if (tid >= 32 && tid < 64)            sB2[tid - 32] = b2[(size_t)l * HH + tid - 32];
            if (tid >= 64 && tid < 64 + NPAR)     sB3[tid - 64] = b3[(size_t)l * NPAR + tid - 64];
            if (tid == 96)                        sB3[23]       = 0.0f;
        }
        __syncthreads();

        // ---- h1 = tanh(x[0:ly] @ W1 + b1) ; x reads coalesced from xT ----
        float h1[HH];
#pragma unroll
        for (int j = 0; j < HH; ++j) h1[j] = sB1[j];
        for (int i = 0; i < ly; ++i) {
            float xi = xT[(size_t)i * B + b];
            const float4* wr = (const float4*)(&sW1[i * HH]);
#pragma unroll
            for (int q = 0; q < HH / 4; ++q) {
                float4 w = wr[q];
                h1[4*q+0] = fmaf(xi, w.x, h1[4*q+0]);
                h1[4*q+1] = fmaf(xi, w.y, h1[4*q+1]);
                h1[4*q+2] = fmaf(xi, w.z, h1[4*q+2]);
                h1[4*q+3] = fmaf(xi, w.w, h1[4*q+3]);
            }
        }
#pragma unroll
        for (int j = 0; j < HH; ++j) h1[j] = fast_tanh(h1[j]);

        // ---- h2 = tanh(h1 @ W2 + b2) ----
        float h2[HH];
#pragma unroll
        for (int j = 0; j < HH; ++j) h2[j] = sB2[j];
#pragma unroll 4
        for (int i = 0; i < HH; ++i) {
            float hi = h1[i];
            const float4* wr = (const float4*)(&sW2[i * HH]);
#pragma unroll
            for (int q = 0; q < HH / 4; ++q) {
                float4 w = wr[q];
                h2[4*q+0] = fmaf(hi, w.x, h2[4*q+0]);
                h2[4*q+1] = fmaf(hi, w.y, h2[4*q+1]);
                h2[4*q+2] = fmaf(hi, w.z, h2[4*q+2]);
                h2[4*q+3] = fmaf(hi, w.w, h2[4*q+3]);
            }
        }
#pragma unroll
        for (int j = 0; j < HH; ++j) h2[j] = fast_tanh(h2[j]);

        // ---- params = h2 @ W3 + b3 (rows padded to 24) ----
#pragma unroll
        for (int k = 0; k < 24; ++k) pr[k] = sB3[k];
#pragma unroll 4
        for (int i = 0; i < HH; ++i) {
            float hi = h2[i];
            const float4* wr = (const float4*)(&sW3[i * 24]);
#pragma unroll
            for (int q = 0; q < 6; ++q) {
                float4 w = wr[q];
                pr[4*q+0] = fmaf(hi, w.x, pr[4*q+0]);
                pr[4*q+1] = fmaf(hi, w.y, pr[4*q+1]);
                pr[4*q+2] = fmaf(hi, w.z, pr[4*q+2]);
                pr[4*q+3] = fmaf(hi, w.w, pr[4*q+3]);
            }
        }
    }

    // ---- spline for dim ly (input x[:, ly], coalesced from xT) ----
    float ld;
    float z = rqs_apply(xT[(size_t)ly * B + b], pr, ld);
    zT[(size_t)ly * B + b]  = z;
    ldp[(size_t)ly * B + b] = ld;
}

extern "C" __global__ void __launch_bounds__(256)
k_finalize(const float* __restrict__ zT, const float* __restrict__ ldp,
           float* __restrict__ zo, float* __restrict__ ldo, int B)
{
    __shared__ float t[64][33];
    const int bbase = blockIdx.x * 64;
    for (int idx = threadIdx.x; idx < 64 * 32; idx += 256) {
        int d = idx >> 6, bb = idx & 63;
        t[bb][d] = zT[(size_t)d * B + bbase + bb];
    }
    __syncthreads();
    for (int idx = threadIdx.x; idx < 64 * 32; idx += 256) {
        int r = idx >> 5, c = idx & 31;
        zo[(size_t)bbase * 32 + idx] = t[r][c];
    }
    if (threadIdx.x < 64) {
        size_t b = bbase + threadIdx.x;
        float s = 0.f;
#pragma unroll
        for (int d = 0; d < 32; ++d) s += ldp[(size_t)d * B + b];
        ldo[b] = s;
    }
}

// ---------------- variant B (fallback if ws too small): direct + atomics ----

extern "C" __global__ void __launch_bounds__(LTPB)
k_layer_direct(const float* __restrict__ x,
               const float* __restrict__ p0,
               const float* __restrict__ w1, const float* __restrict__ b1,
               const float* __restrict__ w2, const float* __restrict__ b2,
               const float* __restrict__ w3, const float* __restrict__ b3,
               float* __restrict__ zo, float* __restrict__ ldo, int B)
{
    __shared__ __align__(16) float sW1[LL * HH];
    __shared__ __align__(16) float sW2[HH * HH];
    __shared__ __align__(16) float sW3[HH * 24];
    __shared__ __align__(16) float sB1[HH];
    __shared__ __align__(16) float sB2[HH];
    __shared__ __align__(16) float sB3[24];

    const int tid = threadIdx.x;
    const int ly  = blockIdx.y;
    const size_t b = (size_t)blockIdx.x * LTPB + tid;

    // load own x row (L1-served after first touch)
    float xr[DD];
    const float4* xrow = (const float4*)(x + b * DD);
#pragma unroll
    for (int q = 0; q < DD / 4; ++q) {
        float4 v = xrow[q];
        xr[4*q+0] = v.x; xr[4*q+1] = v.y; xr[4*q+2] = v.z; xr[4*q+3] = v.w;
    }

    float pr[24];
    if (ly == 0) {
#pragma unroll
        for (int k = 0; k < NPAR; ++k) pr[k] = p0[k];
    } else {
        const int l = ly - 1;
        {
            const float* g1 = w1 + (size_t)l * LL * HH;
            for (int i = tid; i < ly * HH; i += LTPB) sW1[i] = g1[i];
            const float* g2 = w2 + (size_t)l * HH * HH;
            for (int i = tid; i < HH * HH; i += LTPB) sW2[i] = g2[i];
            const float* g3 = w3 + (size_t)l * HH * NPAR;
            for (int i = tid; i < HH * 24; i += LTPB) {
                int r = i / 24, c = i - r * 24;
                sW3[i] = (c < NPAR) ? g3[r * NPAR + c] : 0.0f;
            }
            if (tid < HH)                     sB1[tid]      = b1[(size_t)l * HH + tid];
            if (tid >= 32 && tid < 64)        sB2[tid - 32] = b2[(size_t)l * HH + tid - 32];
            if (tid >= 64 && tid < 64 + NPAR) sB3[tid - 64] = b3[(size_t)l * NPAR + tid - 64];
            if (tid == 96)                    sB3[23]       = 0.0f;
        }
        __syncthreads();

        float h1[HH];
#pragma unroll
        for (int j = 0; j < HH; ++j) h1[j] = sB1[j];
        for (int i = 0; i < ly; ++i) {
            float xi = xr[i];
            const float4* wr = (const float4*)(&sW1[i * HH]);
#pragma unroll
            for (int q = 0; q < HH / 4; ++q) {
                float4 w = wr[q];
                h1[4*q+0] = fmaf(xi, w.x, h1[4*q+0]);
                h1[4*q+1] = fmaf(xi, w.y, h1[4*q+1]);
                h1[4*q+2] = fmaf(xi, w.z, h1[4*q+2]);
                h1[4*q+3] = fmaf(xi, w.w, h1[4*q+3]);
            }
        }
#pragma unroll
        for (int j = 0; j < HH; ++j) h1[j] = fast_tanh(h1[j]);

        float h2[HH];
#pragma unroll
        for (int j = 0; j < HH; ++j) h2[j] = sB2[j];
#pragma unroll 4
        for (int i = 0; i < HH; ++i) {
            float hi = h1[i];
            const float4* wr = (const float4*)(&sW2[i * HH]);
#pragma unroll
            for (int q = 0; q < HH / 4; ++q) {
                float4 w = wr[q];
                h2[4*q+0] = fmaf(hi, w.x, h2[4*q+0]);
                h2[4*q+1] = fmaf(hi, w.y, h2[4*q+1]);
                h2[4*q+2] = fmaf(hi, w.z, h2[4*q+2]);
                h2[4*q+3] = fmaf(hi, w.w, h2[4*q+3]);
            }
        }
#pragma unroll
        for (int j = 0; j < HH; ++j) h2[j] = fast_tanh(h2[j]);

#pragma unroll
        for (int k = 0; k < 24; ++k) pr[k] = sB3[k];
#pragma unroll 4
        for (int i = 0; i < HH; ++i) {
            float hi = h2[i];
            const float4* wr = (const float4*)(&sW3[i * 24]);
#pragma unroll
            for (int q = 0; q < 6; ++q) {
                float4 w = wr[q];
                pr[4*q+0] = fmaf(hi, w.x, pr[4*q+0]);
                pr[4*q+1] = fmaf(hi, w.y, pr[4*q+1]);
                pr[4*q+2] = fmaf(hi, w.z, pr[4*q+2]);
                pr[4*q+3] = fmaf(hi, w.w, pr[4*q+3]);
            }
        }
    }

    float ld;
    float z = rqs_apply(xr[ly], pr, ld);
    zo[b * DD + ly] = z;
    if (ld != 0.0f) unsafeAtomicAdd(&ldo[b], ld);
}

extern "C" void kernel_launch(void* const* d_in, const int* in_sizes, int n_in,
                              void* d_out, int out_size, void* d_ws, size_t ws_size,
                              hipStream_t stream) {
    const float* x  = (const float*)d_in[0];
    const float* p0 = (const float*)d_in[1];
    const float* w1 = (const float*)d_in[2];
    const float* b1 = (const float*)d_in[3];
    const float* w2 = (const float*)d_in[4];
    const float* b2 = (const float*)d_in[5];
    const float* w3 = (const float*)d_in[6];
    const float* b3 = (const float*)d_in[7];

    const int B = in_sizes[0] / DD;            // 65536
    float* zo  = (float*)d_out;
    float* ldo = zo + (size_t)B * DD;

    const size_t plane = (size_t)B * DD * sizeof(float);   // 8 MB
    if (ws_size >= 3 * plane) {
        float* xT  = (float*)d_ws;
        float* zT  = xT + (size_t)B * DD;
        float* ldp = zT + (size_t)B * DD;
        hipLaunchKernelGGL(k_transpose_x, dim3(B / 64), dim3(256), 0, stream, x, xT, B);
        hipLaunchKernelGGL(k_layer, dim3(B / LTPB, DD), dim3(LTPB), 0, stream,
                           xT, p0, w1, b1, w2, b2, w3, b3, zT, ldp, B);
        hipLaunchKernelGGL(k_finalize, dim3(B / 64), dim3(256), 0, stream,
                           zT, ldp, zo, ldo, B);
    } else {
        hipMemsetAsync(ldo, 0, (size_t)B * sizeof(float), stream);
        hipLaunchKernelGGL(k_layer_direct, dim3(B / LTPB, DD), dim3(LTPB), 0, stream,
                           x, p0, w1, b1, w2, b2, w3, b3, zo, ldo, B);
    }
}